// Round 2
// baseline (8115.553 us; speedup 1.0000x reference)
//
#include <hip/hip_runtime.h>
#include <math.h>

#define T_STEPS 512
#define BATCH   256
#define DFEAT   128
#define DIN     257
#define DINP    288   // 257 padded to multiple of 32 (zeros)
#define HID     1024
#define G3      3072
#define OUTD    128

#define W_STRIDE 1032            // LDS row stride (shorts) for W_hh slice: 1024 + 8 pad
#define BUF_F32  13056           // 48 gate-blocks * 272 (16*17) f32
#define HTILE_OFF (BUF_F32 * 4 + 48 * W_STRIDE * 2)       // 52224 + 99072 = 151296
#define LDS_BYTES (HTILE_OFF + 64 * 16 * 2)               // + 2048 = 153344

typedef __bf16 bf16x8 __attribute__((ext_vector_type(8)));
typedef float  f32x4  __attribute__((ext_vector_type(4)));

__device__ __forceinline__ unsigned short f2bf(float f) {
    unsigned int u = __float_as_uint(f);
    u += 0x7FFF + ((u >> 16) & 1);   // round-to-nearest-even
    return (unsigned short)(u >> 16);
}

// Build xt[t][b][c] (bf16, zero-padded to DINP) from x[b][t][d], mask[b][t][d], ti[b][t]
__global__ void build_xt(const float* __restrict__ x, const float* __restrict__ mask,
                         const float* __restrict__ ti, unsigned short* __restrict__ xt) {
    const int N = T_STEPS * BATCH * DINP;
    for (int idx = blockIdx.x * blockDim.x + threadIdx.x; idx < N;
         idx += gridDim.x * blockDim.x) {
        int c   = idx % DINP;
        int rem = idx / DINP;
        int b   = rem % BATCH;
        int t   = rem / BATCH;
        float v;
        if (c < DFEAT)            v = x[(b * T_STEPS + t) * DFEAT + c];
        else if (c < 2 * DFEAT)   v = mask[(b * T_STEPS + t) * DFEAT + (c - DFEAT)];
        else if (c == 2 * DFEAT)  v = ti[b * T_STEPS + t];
        else                      v = 0.f;
        xt[idx] = f2bf(v);
    }
}

// Persistent GRU: 256 blocks (1/CU), block = (unit-tile ut, batch-group g).
// W_hh slice LDS-resident all 512 steps; W_ih frags in regs; waves K-split.
// Sync: per-block slot flags (no RMW contention), 64-thread poll w/ s_sleep.
// h exchange: stores write-through (agent-scope atomic, drained before flag);
// loads are PLAIN CACHED loads after a per-step agent acquire fence
// (buffer_inv): first toucher per XCD fetches from IF, ~7 same-group
// blocks/XCD then hit L2 instead of paying the IF round trip each.
__global__ __launch_bounds__(256, 1) void gru_persist(
    const unsigned short* __restrict__ xt,
    const float* __restrict__ W_ih, const float* __restrict__ W_hh,
    const float* __restrict__ b_ih, const float* __restrict__ b_hh,
    unsigned long long* hb0, unsigned long long* hb1,
    float* __restrict__ hF, unsigned int* flags)
{
    extern __shared__ char smem[];
    float* buf = (float*)smem;                                    // 52224 B
    unsigned short* wlds  = (unsigned short*)(smem + BUF_F32 * 4); // 48 x 1032 shorts
    unsigned short* htile = (unsigned short*)(smem + HTILE_OFF);   // 64 x 16 shorts

    const int tid = threadIdx.x;
    const int w   = tid >> 6;          // wave 0..3
    const int ln  = tid & 15;          // unit lane / A row lane
    const int q   = (tid & 63) >> 4;   // quad
    const int g   = blockIdx.x >> 6;   // batch group 0..3
    const int ut  = blockIdx.x & 63;   // unit tile 0..63
    const int u0  = ut * 16;
    const int bb  = g * 64;

    // ---- load W_hh slice into LDS (f32 -> bf16), rows = gate*16 + u ----
    for (int i = tid; i < 48 * 512; i += 256) {
        int row = i >> 9;                 // 0..47
        int c2  = (i & 511) * 2;          // 0..1022 step 2
        int grow = (row >> 4) * HID + u0 + (row & 15);
        const float* src = W_hh + (size_t)grow * HID + c2;
        unsigned int lo = f2bf(src[0]), hi = f2bf(src[1]);
        *(unsigned int*)(&wlds[row * W_STRIDE + c2]) = lo | (hi << 16);
    }

    // ---- W_ih fragments into registers: wave w owns x-chunks {w, w+4, w+8(<9)} ----
    bf16x8 xw[3][3];   // [chunk][gate r,z,n]
    const int nxc = (w == 0) ? 3 : 2;
    #pragma unroll
    for (int xi = 0; xi < 3; xi++) {
        int cx = w + xi * 4;
        #pragma unroll
        for (int G = 0; G < 3; G++) {
            unsigned short tmp[8];
            #pragma unroll
            for (int j = 0; j < 8; j++) {
                int col = cx * 32 + q * 8 + j;
                float f = (cx < 9 && col < DIN)
                    ? W_ih[(size_t)(G * HID + u0 + ln) * DIN + col] : 0.f;
                tmp[j] = f2bf(f);
            }
            xw[xi][G] = *(bf16x8*)tmp;
        }
    }

    // ---- biases (per lane unit), fp32 master h in regs ----
    const int gu = u0 + ln;
    const float bR  = b_ih[gu]            + b_hh[gu];
    const float bZ  = b_ih[HID + gu]      + b_hh[HID + gu];
    const float bIN = b_ih[2 * HID + gu];
    const float bHN = b_hh[2 * HID + gu];
    float hreg[4] = {0.f, 0.f, 0.f, 0.f};

    __syncthreads();

    unsigned long long* hbufs[2] = {hb0, hb1};

    for (int t = 0; t < T_STEPS; t++) {
        const unsigned long long* hrd = hbufs[t & 1];
        unsigned long long* hwr = hbufs[(t + 1) & 1];

        f32x4 aR[4]  = {{0,0,0,0},{0,0,0,0},{0,0,0,0},{0,0,0,0}};
        f32x4 aZ[4]  = {{0,0,0,0},{0,0,0,0},{0,0,0,0},{0,0,0,0}};
        f32x4 aIN[4] = {{0,0,0,0},{0,0,0,0},{0,0,0,0},{0,0,0,0}};
        f32x4 aHN[4] = {{0,0,0,0},{0,0,0,0},{0,0,0,0},{0,0,0,0}};

        // ---- x-part (no h dependency — overlaps producer tail) ----
        const unsigned short* xrow = xt + (size_t)t * BATCH * DINP;
        #pragma unroll
        for (int xi = 0; xi < 3; xi++) {
            if (xi < nxc) {
                int kx = (w + xi * 4) * 32;
                #pragma unroll
                for (int s = 0; s < 4; s++) {
                    bf16x8 a = *(const bf16x8*)(xrow + (size_t)(bb + s * 16 + ln) * DINP + kx + q * 8);
                    aR[s]  = __builtin_amdgcn_mfma_f32_16x16x32_bf16(a, xw[xi][0], aR[s],  0, 0, 0);
                    aZ[s]  = __builtin_amdgcn_mfma_f32_16x16x32_bf16(a, xw[xi][1], aZ[s],  0, 0, 0);
                    aIN[s] = __builtin_amdgcn_mfma_f32_16x16x32_bf16(a, xw[xi][2], aIN[s], 0, 0, 0);
                }
            }
        }

        // ---- wait for h(t): 64 per-block slots, 64-thread poll w/ backoff ----
        if (t > 0 && tid < 64) {
            const unsigned int* slot = flags + ((size_t)(t - 1) * 4 + g) * 64 + tid;
            while (__hip_atomic_load(slot, __ATOMIC_RELAXED,
                                     __HIP_MEMORY_SCOPE_AGENT) == 0u)
                __builtin_amdgcn_s_sleep(1);
        }
        __syncthreads();   // [A]

        // ---- acquire fence: invalidate L1/L2 so cached h loads see step t-1
        //      data (writers drained to coherence point before their flags) ----
        __builtin_amdgcn_fence(__ATOMIC_ACQUIRE, "agent");

        // ---- h-part: preload ALL fragments via plain cached 16B loads ----
        const unsigned short* hrd16 = (const unsigned short*)hrd;
        bf16x8 hfrag[8][4];
        #pragma unroll
        for (int ci = 0; ci < 8; ci++) {
            int k0 = (w + ci * 4) * 32;
            #pragma unroll
            for (int s = 0; s < 4; s++) {
                hfrag[ci][s] = *(const bf16x8*)(
                    hrd16 + (size_t)(bb + s * 16 + ln) * HID + k0 + q * 8);
            }
        }
        // ---- then MFMA from registers ----
        #pragma unroll
        for (int ci = 0; ci < 8; ci++) {
            int k0 = (w + ci * 4) * 32;
            bf16x8 br = *(const bf16x8*)(&wlds[(0  + ln) * W_STRIDE + k0 + q * 8]);
            bf16x8 bz = *(const bf16x8*)(&wlds[(16 + ln) * W_STRIDE + k0 + q * 8]);
            bf16x8 bn = *(const bf16x8*)(&wlds[(32 + ln) * W_STRIDE + k0 + q * 8]);
            #pragma unroll
            for (int s = 0; s < 4; s++) {
                aR[s]  = __builtin_amdgcn_mfma_f32_16x16x32_bf16(hfrag[ci][s], br, aR[s],  0, 0, 0);
                aZ[s]  = __builtin_amdgcn_mfma_f32_16x16x32_bf16(hfrag[ci][s], bz, aZ[s],  0, 0, 0);
                aHN[s] = __builtin_amdgcn_mfma_f32_16x16x32_bf16(hfrag[ci][s], bn, aHN[s], 0, 0, 0);
            }
        }

        // ---- cross-wave K-reduction: write partials for quarters we don't own ----
        #pragma unroll
        for (int s = 0; s < 4; s++) {
            if (s != w) {
                int j = w - (w > s ? 1 : 0);
                int base = (s * 3 + j) * 4;
                #pragma unroll
                for (int r = 0; r < 4; r++) {
                    int ro = (q * 4 + r) * 17 + ln;
                    buf[(base + 0) * 272 + ro] = aR[s][r];
                    buf[(base + 1) * 272 + ro] = aZ[s][r];
                    buf[(base + 2) * 272 + ro] = aIN[s][r];
                    buf[(base + 3) * 272 + ro] = aHN[s][r];
                }
            }
        }
        __syncthreads();   // [C]

        f32x4 myR  = (w == 0) ? aR[0]  : (w == 1) ? aR[1]  : (w == 2) ? aR[2]  : aR[3];
        f32x4 myZ  = (w == 0) ? aZ[0]  : (w == 1) ? aZ[1]  : (w == 2) ? aZ[2]  : aZ[3];
        f32x4 myIN = (w == 0) ? aIN[0] : (w == 1) ? aIN[1] : (w == 2) ? aIN[2] : aIN[3];
        f32x4 myHN = (w == 0) ? aHN[0] : (w == 1) ? aHN[1] : (w == 2) ? aHN[2] : aHN[3];

        float R[4], Z[4], IN[4], HN[4];
        #pragma unroll
        for (int r = 0; r < 4; r++) { R[r] = myR[r]; Z[r] = myZ[r]; IN[r] = myIN[r]; HN[r] = myHN[r]; }
        #pragma unroll
        for (int j = 0; j < 3; j++) {
            int base = (w * 3 + j) * 4;
            #pragma unroll
            for (int r = 0; r < 4; r++) {
                int ro = (q * 4 + r) * 17 + ln;
                R[r]  += buf[(base + 0) * 272 + ro];
                Z[r]  += buf[(base + 1) * 272 + ro];
                IN[r] += buf[(base + 2) * 272 + ro];
                HN[r] += buf[(base + 3) * 272 + ro];
            }
        }

        // ---- gates + state update; h(t+1) bf16 into LDS tile [batch][unit] ----
        #pragma unroll
        for (int r = 0; r < 4; r++) {
            float pr = R[r] + bR;
            float pz = Z[r] + bZ;
            float rg = 1.f / (1.f + expf(-pr));
            float zg = 1.f / (1.f + expf(-pz));
            float ng = tanhf(IN[r] + bIN + rg * (HN[r] + bHN));
            float hn = (1.f - zg) * ng + zg * hreg[r];
            hreg[r] = hn;
            int lb = w * 16 + q * 4 + r;              // local batch 0..63
            htile[lb * 16 + ln] = f2bf(hn);
            if (t == T_STEPS - 1) hF[(size_t)(bb + lb) * HID + gu] = hn;
        }
        __syncthreads();   // [E] htile complete

        // ---- packed coherent h store: thread i -> (batch i/4, unit-quad i%4) ----
        {
            int lb = tid >> 2;
            int ug = (tid & 3) * 4;
            unsigned long long pk = *(const unsigned long long*)(&htile[lb * 16 + ug]);
            __hip_atomic_store(hwr + ((((size_t)(bb + lb)) * HID + u0 + ug) >> 2), pk,
                               __ATOMIC_RELAXED, __HIP_MEMORY_SCOPE_AGENT);
        }

        __syncthreads();   // [D] vmcnt(0) drain: all h stores coherent-visible
        if (tid == 0)
            __hip_atomic_store(flags + ((size_t)t * 4 + g) * 64 + ut, 1u,
                               __ATOMIC_RELAXED, __HIP_MEMORY_SCOPE_AGENT);
    }
}

// out[b][o] = h[b] . W_out[o] + b_out[o]
__global__ void out_proj(const float* __restrict__ h, const float* __restrict__ Wout,
                         const float* __restrict__ bout, float* __restrict__ out) {
    int b = blockIdx.x;    // 256
    int o = threadIdx.x;   // 128
    const float* hr = h + (size_t)b * HID;
    const float* wr = Wout + (size_t)o * HID;
    float s0 = 0.f, s1 = 0.f, s2 = 0.f, s3 = 0.f;
    for (int u = 0; u < HID; u += 4) {
        s0 += hr[u + 0] * wr[u + 0];
        s1 += hr[u + 1] * wr[u + 1];
        s2 += hr[u + 2] * wr[u + 2];
        s3 += hr[u + 3] * wr[u + 3];
    }
    out[b * OUTD + o] = (s0 + s1) + (s2 + s3) + bout[o];
}

extern "C" void kernel_launch(void* const* d_in, const int* in_sizes, int n_in,
                              void* d_out, int out_size, void* d_ws, size_t ws_size,
                              hipStream_t stream) {
    const float* x     = (const float*)d_in[0];
    const float* mask  = (const float*)d_in[1];
    const float* ti    = (const float*)d_in[2];
    const float* W_ih  = (const float*)d_in[3];
    const float* W_hh  = (const float*)d_in[4];
    const float* b_ih  = (const float*)d_in[5];
    const float* b_hh  = (const float*)d_in[6];
    const float* W_out = (const float*)d_in[7];
    const float* b_out = (const float*)d_in[8];
    float* out = (float*)d_out;

    char* ws = (char*)d_ws;
    unsigned int* flags     = (unsigned int*)ws;                        // 512 KB (512*4*64*4)
    unsigned long long* hb0 = (unsigned long long*)(ws + 524288);       // 512 KB
    unsigned long long* hb1 = (unsigned long long*)(ws + 2 * 524288);   // 512 KB
    float* hF               = (float*)(ws + 3 * 524288);                // 1 MB
    unsigned short* xtb     = (unsigned short*)(ws + 3 * 524288 + 1048576);

    // zero flags + h(0) (contiguous)
    (void)hipMemsetAsync(ws, 0, 2 * 524288, stream);

    build_xt<<<4096, 256, 0, stream>>>(x, mask, ti, xtb);

    (void)hipFuncSetAttribute((const void*)gru_persist,
                              hipFuncAttributeMaxDynamicSharedMemorySize, LDS_BYTES);

    gru_persist<<<256, 256, LDS_BYTES, stream>>>(xtb, W_ih, W_hh, b_ih, b_hh,
                                                 hb0, hb1, hF, flags);

    out_proj<<<256, 128, 0, stream>>>(hF, W_out, b_out, out);
}

// Round 3
// 5147.387 us; speedup vs baseline: 1.5766x; 1.5766x over previous
//
#include <hip/hip_runtime.h>
#include <math.h>

#define T_STEPS 512
#define BATCH   256
#define DFEAT   128
#define DIN     257
#define DINP    288   // 257 padded to multiple of 32 (zeros)
#define HID     1024
#define OUTD    128

#define W_STRIDE 1032            // LDS row stride (shorts) for W_hh slice: 1024 + 8 pad
#define BUF_F32  13056           // 48 gate-blocks * 272 (16*17) f32
#define HTILE_OFF (BUF_F32 * 4 + 48 * W_STRIDE * 2)       // 52224 + 99072 = 151296
#define LDS_BYTES (HTILE_OFF + 64 * 16 * 2)               // + 2048 = 153344

typedef __bf16 bf16x8 __attribute__((ext_vector_type(8)));
typedef float  f32x4  __attribute__((ext_vector_type(4)));
typedef unsigned int u32x4 __attribute__((ext_vector_type(4)));

__device__ __forceinline__ unsigned short f2bf(float f) {
    unsigned int u = __float_as_uint(f);
    u += 0x7FFF + ((u >> 16) & 1);   // round-to-nearest-even
    return (unsigned short)(u >> 16);
}

// 16B cache-bypassing load straight from the coherence point (L3).
// sc0 sc1 = system-scope: misses L1/L2, reads fresh data (same visibility
// semantics as the proven agent-scope atomic pair, half the requests).
__device__ __forceinline__ bf16x8 load_h16(const unsigned short* p) {
    u32x4 r;
    asm volatile("global_load_dwordx4 %0, %1, off sc0 sc1"
                 : "=v"(r) : "v"(p));
    union { u32x4 u; bf16x8 v; } c; c.u = r;
    return c.v;
}

// Build xt[t][b][c] (bf16, zero-padded to DINP) from x[b][t][d], mask[b][t][d], ti[b][t]
__global__ void build_xt(const float* __restrict__ x, const float* __restrict__ mask,
                         const float* __restrict__ ti, unsigned short* __restrict__ xt) {
    const int N = T_STEPS * BATCH * DINP;
    for (int idx = blockIdx.x * blockDim.x + threadIdx.x; idx < N;
         idx += gridDim.x * blockDim.x) {
        int c   = idx % DINP;
        int rem = idx / DINP;
        int b   = rem % BATCH;
        int t   = rem / BATCH;
        float v;
        if (c < DFEAT)            v = x[(b * T_STEPS + t) * DFEAT + c];
        else if (c < 2 * DFEAT)   v = mask[(b * T_STEPS + t) * DFEAT + (c - DFEAT)];
        else if (c == 2 * DFEAT)  v = ti[b * T_STEPS + t];
        else                      v = 0.f;
        xt[idx] = f2bf(v);
    }
}

// Persistent GRU: 256 blocks (1/CU), block = (unit-tile ut, batch-group g).
// W_hh slice LDS-resident all 512 steps; W_ih frags in regs; waves K-split.
// h exchange (round-0 proven visibility scheme, restructured sync):
//   stores: agent-scope write-through atomics -> PER-WAVE vmcnt(0) drain ->
//           per-wave flag (256 slots/group/step). No block-wide [E]/[D]
//           barriers: htile transpose + packed-store read are wave-closed.
//   loads:  16B sc0+sc1 asm loads (no fence, no cache invalidate).
__global__ __launch_bounds__(256, 1) void gru_persist(
    const unsigned short* __restrict__ xt,
    const float* __restrict__ W_ih, const float* __restrict__ W_hh,
    const float* __restrict__ b_ih, const float* __restrict__ b_hh,
    unsigned long long* hb0, unsigned long long* hb1,
    float* __restrict__ hF, unsigned int* flags)
{
    extern __shared__ char smem[];
    float* buf = (float*)smem;                                    // 52224 B
    unsigned short* wlds  = (unsigned short*)(smem + BUF_F32 * 4); // 48 x 1032 shorts
    unsigned short* htile = (unsigned short*)(smem + HTILE_OFF);   // 64 x 16 shorts

    const int tid = threadIdx.x;
    const int w   = tid >> 6;          // wave 0..3
    const int ln  = tid & 15;          // unit lane / A row lane
    const int q   = (tid & 63) >> 4;   // quad
    const int g   = blockIdx.x >> 6;   // batch group 0..3
    const int ut  = blockIdx.x & 63;   // unit tile 0..63
    const int u0  = ut * 16;
    const int bb  = g * 64;

    // ---- load W_hh slice into LDS (f32 -> bf16), rows = gate*16 + u ----
    for (int i = tid; i < 48 * 512; i += 256) {
        int row = i >> 9;                 // 0..47
        int c2  = (i & 511) * 2;          // 0..1022 step 2
        int grow = (row >> 4) * HID + u0 + (row & 15);
        const float* src = W_hh + (size_t)grow * HID + c2;
        unsigned int lo = f2bf(src[0]), hi = f2bf(src[1]);
        *(unsigned int*)(&wlds[row * W_STRIDE + c2]) = lo | (hi << 16);
    }

    // ---- W_ih fragments into registers: wave w owns x-chunks {w, w+4, w+8(<9)} ----
    bf16x8 xw[3][3];   // [chunk][gate r,z,n]
    const int nxc = (w == 0) ? 3 : 2;
    #pragma unroll
    for (int xi = 0; xi < 3; xi++) {
        int cx = w + xi * 4;
        #pragma unroll
        for (int G = 0; G < 3; G++) {
            unsigned short tmp[8];
            #pragma unroll
            for (int j = 0; j < 8; j++) {
                int col = cx * 32 + q * 8 + j;
                float f = (cx < 9 && col < DIN)
                    ? W_ih[(size_t)(G * HID + u0 + ln) * DIN + col] : 0.f;
                tmp[j] = f2bf(f);
            }
            xw[xi][G] = *(bf16x8*)tmp;
        }
    }

    // ---- biases (per lane unit), fp32 master h in regs ----
    const int gu = u0 + ln;
    const float bR  = b_ih[gu]            + b_hh[gu];
    const float bZ  = b_ih[HID + gu]      + b_hh[HID + gu];
    const float bIN = b_ih[2 * HID + gu];
    const float bHN = b_hh[2 * HID + gu];
    float hreg[4] = {0.f, 0.f, 0.f, 0.f};

    __syncthreads();

    unsigned long long* hbufs[2] = {hb0, hb1};

    for (int t = 0; t < T_STEPS; t++) {
        const unsigned long long* hrd = hbufs[t & 1];
        unsigned long long* hwr = hbufs[(t + 1) & 1];

        f32x4 aR[4]  = {{0,0,0,0},{0,0,0,0},{0,0,0,0},{0,0,0,0}};
        f32x4 aZ[4]  = {{0,0,0,0},{0,0,0,0},{0,0,0,0},{0,0,0,0}};
        f32x4 aIN[4] = {{0,0,0,0},{0,0,0,0},{0,0,0,0},{0,0,0,0}};
        f32x4 aHN[4] = {{0,0,0,0},{0,0,0,0},{0,0,0,0},{0,0,0,0}};

        // ---- x-part (no h dependency — overlaps producer tail) ----
        const unsigned short* xrow = xt + (size_t)t * BATCH * DINP;
        #pragma unroll
        for (int xi = 0; xi < 3; xi++) {
            if (xi < nxc) {
                int kx = (w + xi * 4) * 32;
                #pragma unroll
                for (int s = 0; s < 4; s++) {
                    bf16x8 a = *(const bf16x8*)(xrow + (size_t)(bb + s * 16 + ln) * DINP + kx + q * 8);
                    aR[s]  = __builtin_amdgcn_mfma_f32_16x16x32_bf16(a, xw[xi][0], aR[s],  0, 0, 0);
                    aZ[s]  = __builtin_amdgcn_mfma_f32_16x16x32_bf16(a, xw[xi][1], aZ[s],  0, 0, 0);
                    aIN[s] = __builtin_amdgcn_mfma_f32_16x16x32_bf16(a, xw[xi][2], aIN[s], 0, 0, 0);
                }
            }
        }

        // ---- wait for h(t): 256 per-wave slots, every thread polls one ----
        if (t > 0) {
            const unsigned int* slot =
                flags + (((size_t)(t - 1) * 4 + g) << 8) + tid;
            while (__hip_atomic_load(slot, __ATOMIC_RELAXED,
                                     __HIP_MEMORY_SCOPE_AGENT) == 0u)
                __builtin_amdgcn_s_sleep(1);
        }
        __syncthreads();   // [A]

        // ---- h-part: preload ALL fragments via 16B sc0+sc1 loads ----
        const unsigned short* hrd16 = (const unsigned short*)hrd;
        bf16x8 hfrag[8][4];
        __builtin_amdgcn_sched_barrier(0);
        #pragma unroll
        for (int ci = 0; ci < 8; ci++) {
            int k0 = (w + ci * 4) * 32;
            #pragma unroll
            for (int s = 0; s < 4; s++) {
                hfrag[ci][s] = load_h16(
                    hrd16 + (size_t)(bb + s * 16 + ln) * HID + k0 + q * 8);
            }
        }
        asm volatile("s_waitcnt vmcnt(0)" ::: "memory");
        __builtin_amdgcn_sched_barrier(0);   // rule #18: pin MFMAs after the wait

        // ---- then MFMA from registers ----
        #pragma unroll
        for (int ci = 0; ci < 8; ci++) {
            int k0 = (w + ci * 4) * 32;
            bf16x8 br = *(const bf16x8*)(&wlds[(0  + ln) * W_STRIDE + k0 + q * 8]);
            bf16x8 bz = *(const bf16x8*)(&wlds[(16 + ln) * W_STRIDE + k0 + q * 8]);
            bf16x8 bn = *(const bf16x8*)(&wlds[(32 + ln) * W_STRIDE + k0 + q * 8]);
            #pragma unroll
            for (int s = 0; s < 4; s++) {
                aR[s]  = __builtin_amdgcn_mfma_f32_16x16x32_bf16(hfrag[ci][s], br, aR[s],  0, 0, 0);
                aZ[s]  = __builtin_amdgcn_mfma_f32_16x16x32_bf16(hfrag[ci][s], bz, aZ[s],  0, 0, 0);
                aHN[s] = __builtin_amdgcn_mfma_f32_16x16x32_bf16(hfrag[ci][s], bn, aHN[s], 0, 0, 0);
            }
        }

        // ---- cross-wave K-reduction: write partials for quarters we don't own ----
        #pragma unroll
        for (int s = 0; s < 4; s++) {
            if (s != w) {
                int j = w - (w > s ? 1 : 0);
                int base = (s * 3 + j) * 4;
                #pragma unroll
                for (int r = 0; r < 4; r++) {
                    int ro = (q * 4 + r) * 17 + ln;
                    buf[(base + 0) * 272 + ro] = aR[s][r];
                    buf[(base + 1) * 272 + ro] = aZ[s][r];
                    buf[(base + 2) * 272 + ro] = aIN[s][r];
                    buf[(base + 3) * 272 + ro] = aHN[s][r];
                }
            }
        }
        __syncthreads();   // [C]

        f32x4 myR  = (w == 0) ? aR[0]  : (w == 1) ? aR[1]  : (w == 2) ? aR[2]  : aR[3];
        f32x4 myZ  = (w == 0) ? aZ[0]  : (w == 1) ? aZ[1]  : (w == 2) ? aZ[2]  : aZ[3];
        f32x4 myIN = (w == 0) ? aIN[0] : (w == 1) ? aIN[1] : (w == 2) ? aIN[2] : aIN[3];
        f32x4 myHN = (w == 0) ? aHN[0] : (w == 1) ? aHN[1] : (w == 2) ? aHN[2] : aHN[3];

        float R[4], Z[4], IN[4], HN[4];
        #pragma unroll
        for (int r = 0; r < 4; r++) { R[r] = myR[r]; Z[r] = myZ[r]; IN[r] = myIN[r]; HN[r] = myHN[r]; }
        #pragma unroll
        for (int j = 0; j < 3; j++) {
            int base = (w * 3 + j) * 4;
            #pragma unroll
            for (int r = 0; r < 4; r++) {
                int ro = (q * 4 + r) * 17 + ln;
                R[r]  += buf[(base + 0) * 272 + ro];
                Z[r]  += buf[(base + 1) * 272 + ro];
                IN[r] += buf[(base + 2) * 272 + ro];
                HN[r] += buf[(base + 3) * 272 + ro];
            }
        }

        // ---- gates + state update; h(t+1) bf16 into LDS tile [batch][unit].
        //      Wave-closed: wave w writes rows 16w..16w+15 and only wave w's
        //      threads read them back (lgkmcnt, no barrier needed). ----
        #pragma unroll
        for (int r = 0; r < 4; r++) {
            float pr = R[r] + bR;
            float pz = Z[r] + bZ;
            float rg = 1.f / (1.f + expf(-pr));
            float zg = 1.f / (1.f + expf(-pz));
            float ng = tanhf(IN[r] + bIN + rg * (HN[r] + bHN));
            float hn = (1.f - zg) * ng + zg * hreg[r];
            hreg[r] = hn;
            int lb = w * 16 + q * 4 + r;              // local batch 0..63
            htile[lb * 16 + ln] = f2bf(hn);
            if (t == T_STEPS - 1) hF[(size_t)(bb + lb) * HID + gu] = hn;
        }

        // ---- packed coherent h store: thread i -> (batch i/4, unit-quad i%4).
        //      tid>>2 stays inside this wave's 16-batch htile slice. ----
        {
            int lb = tid >> 2;
            int ug = (tid & 3) * 4;
            unsigned long long pk = *(const unsigned long long*)(&htile[lb * 16 + ug]);
            __hip_atomic_store(hwr + ((((size_t)(bb + lb)) * HID + u0 + ug) >> 2), pk,
                               __ATOMIC_RELAXED, __HIP_MEMORY_SCOPE_AGENT);
        }

        // ---- per-wave release: drain own stores, then set own flag slot ----
        asm volatile("s_waitcnt vmcnt(0)" ::: "memory");
        if ((tid & 63) == 0)
            __hip_atomic_store(flags + (((size_t)t * 4 + g) << 8) + (ut << 2) + w, 1u,
                               __ATOMIC_RELAXED, __HIP_MEMORY_SCOPE_AGENT);
    }
}

// out[b][o] = h[b] . W_out[o] + b_out[o]
__global__ void out_proj(const float* __restrict__ h, const float* __restrict__ Wout,
                         const float* __restrict__ bout, float* __restrict__ out) {
    int b = blockIdx.x;    // 256
    int o = threadIdx.x;   // 128
    const float* hr = h + (size_t)b * HID;
    const float* wr = Wout + (size_t)o * HID;
    float s0 = 0.f, s1 = 0.f, s2 = 0.f, s3 = 0.f;
    for (int u = 0; u < HID; u += 4) {
        s0 += hr[u + 0] * wr[u + 0];
        s1 += hr[u + 1] * wr[u + 1];
        s2 += hr[u + 2] * wr[u + 2];
        s3 += hr[u + 3] * wr[u + 3];
    }
    out[b * OUTD + o] = (s0 + s1) + (s2 + s3) + bout[o];
}

extern "C" void kernel_launch(void* const* d_in, const int* in_sizes, int n_in,
                              void* d_out, int out_size, void* d_ws, size_t ws_size,
                              hipStream_t stream) {
    const float* x     = (const float*)d_in[0];
    const float* mask  = (const float*)d_in[1];
    const float* ti    = (const float*)d_in[2];
    const float* W_ih  = (const float*)d_in[3];
    const float* W_hh  = (const float*)d_in[4];
    const float* b_ih  = (const float*)d_in[5];
    const float* b_hh  = (const float*)d_in[6];
    const float* W_out = (const float*)d_in[7];
    const float* b_out = (const float*)d_in[8];
    float* out = (float*)d_out;

    char* ws = (char*)d_ws;
    unsigned int* flags     = (unsigned int*)ws;                        // 2 MB (512*4*256*4)
    unsigned long long* hb0 = (unsigned long long*)(ws + 2097152);      // 512 KB
    unsigned long long* hb1 = (unsigned long long*)(ws + 2621440);      // 512 KB
    float* hF               = (float*)(ws + 3145728);                   // 1 MB
    unsigned short* xtb     = (unsigned short*)(ws + 4194304);          // 75.5 MB

    // zero flags + h(0) (contiguous)
    (void)hipMemsetAsync(ws, 0, 2621440, stream);

    build_xt<<<4096, 256, 0, stream>>>(x, mask, ti, xtb);

    (void)hipFuncSetAttribute((const void*)gru_persist,
                              hipFuncAttributeMaxDynamicSharedMemorySize, LDS_BYTES);

    gru_persist<<<256, 256, LDS_BYTES, stream>>>(xtb, W_ih, W_hh, b_ih, b_hh,
                                                 hb0, hb1, hF, flags);

    out_proj<<<256, 128, 0, stream>>>(hF, W_out, b_out, out);
}

// Round 4
// 3570.160 us; speedup vs baseline: 2.2732x; 1.4418x over previous
//
#include <hip/hip_runtime.h>
#include <math.h>

#define T_STEPS 512
#define BATCH   256
#define DFEAT   128
#define DIN     257
#define DINP    288   // 257 padded to multiple of 32 (zeros)
#define HID     1024
#define OUTD    128

// New decomposition: 256 blocks = 32 unit-tiles (32 units) x 8 batch-groups (32 batches).
// Halves the redundant h-broadcast read volume: 16 MB/step from IF (was 32).
#define UTN     32    // unit tiles
#define BGN     8     // batch groups
#define BPG     32    // batches per group

// LDS: reduction buf (52224) + W_ih bf16 (96 x 296 shorts = 56832) + per-wave htile (4 x 16 x 24 shorts = 3072)
#define WIH_STRIDE 296
#define WIH_OFF   52224
#define HTILE_OFF (52224 + 56832)          // 109056
#define LDS_BYTES (HTILE_OFF + 3072)       // 112128

typedef __bf16 bf16x8 __attribute__((ext_vector_type(8)));
typedef float  f32x4  __attribute__((ext_vector_type(4)));
typedef unsigned int u32x4 __attribute__((ext_vector_type(4)));

__device__ __forceinline__ unsigned short f2bf(float f) {
    unsigned int u = __float_as_uint(f);
    u += 0x7FFF + ((u >> 16) & 1);   // round-to-nearest-even
    return (unsigned short)(u >> 16);
}

// 16B cache-bypassing load straight from the coherence point (L3).
__device__ __forceinline__ bf16x8 load_h16(const unsigned short* p) {
    u32x4 r;
    asm volatile("global_load_dwordx4 %0, %1, off sc0 sc1"
                 : "=v"(r) : "v"(p));
    union { u32x4 u; bf16x8 v; } c; c.u = r;
    return c.v;
}

// Build xt[t][b][c] (bf16, zero-padded to DINP) from x[b][t][d], mask[b][t][d], ti[b][t]
__global__ void build_xt(const float* __restrict__ x, const float* __restrict__ mask,
                         const float* __restrict__ ti, unsigned short* __restrict__ xt) {
    const int N = T_STEPS * BATCH * DINP;
    for (int idx = blockIdx.x * blockDim.x + threadIdx.x; idx < N;
         idx += gridDim.x * blockDim.x) {
        int c   = idx % DINP;
        int rem = idx / DINP;
        int b   = rem % BATCH;
        int t   = rem / BATCH;
        float v;
        if (c < DFEAT)            v = x[(b * T_STEPS + t) * DFEAT + c];
        else if (c < 2 * DFEAT)   v = mask[(b * T_STEPS + t) * DFEAT + (c - DFEAT)];
        else if (c == 2 * DFEAT)  v = ti[b * T_STEPS + t];
        else                      v = 0.f;
        xt[idx] = f2bf(v);
    }
}

// Persistent GRU: 256 blocks (1/CU), block = (unit-tile ut: 32 units, batch-group g: 32 batches).
// W_hh slice REGISTER-resident (192 VGPR/thread, K-split per wave — no per-step W ds_reads).
// W_ih bf16 in LDS. h exchange: agent-scope WT stores + per-wave vmcnt drain + per-wave
// flags; 16B sc0+sc1 loads. Sync graph: 32 blocks/group (128 producer-wave flags).
__global__ __launch_bounds__(256, 1) void gru_persist(
    const unsigned short* __restrict__ xt,
    const float* __restrict__ W_ih, const float* __restrict__ W_hh,
    const float* __restrict__ b_ih, const float* __restrict__ b_hh,
    unsigned long long* hb0, unsigned long long* hb1,
    float* __restrict__ hF, unsigned int* flags)
{
    extern __shared__ char smem[];
    float* buf = (float*)smem;                                    // 52224 B
    unsigned short* wih   = (unsigned short*)(smem + WIH_OFF);    // 96 x 296 shorts
    unsigned short* htile = (unsigned short*)(smem + HTILE_OFF);  // 4 x 16 x 24 shorts

    const int tid = threadIdx.x;
    const int w   = tid >> 6;          // wave 0..3 (K-split)
    const int ln  = tid & 15;          // A-row / B-col lane
    const int q   = (tid & 63) >> 4;   // quad (K-slice within fragment)
    const int g   = blockIdx.x >> 5;   // batch group 0..7
    const int ut  = blockIdx.x & 31;   // unit tile 0..31
    const int u0  = ut * 32;
    const int bb  = g * BPG;

    // wave w owns output quadrant (s,n) = (w>>1, w&1) of the 32x32 tile
    const int ws = w >> 1;             // batch-subtile owned
    const int wn = w & 1;              // unit-subtile owned

    // ---- W_ih slice into LDS (f32 -> bf16), rows = gate*32 + ul, 296-short stride ----
    for (int i = tid; i < 96 * 144; i += 256) {
        int row = i / 144;                // 0..95
        int c2  = (i % 144) * 2;          // 0..286 step 2
        int grow = (row >> 5) * HID + u0 + (row & 31);
        const float* src = W_ih + (size_t)grow * DIN;
        unsigned int lo = (c2     < DIN) ? f2bf(src[c2])     : 0u;
        unsigned int hi = (c2 + 1 < DIN) ? f2bf(src[c2 + 1]) : 0u;
        *(unsigned int*)(&wih[row * WIH_STRIDE + c2]) = lo | (hi << 16);
    }

    // ---- W_hh fragments into REGISTERS: wave w owns K-chunks {w, w+4, ..., w+28} ----
    bf16x8 whh[8][3][2];   // [K-chunk][gate r,z,n][unit-subtile]
    #pragma unroll
    for (int ci = 0; ci < 8; ci++) {
        int k0 = (w + ci * 4) * 32;
        #pragma unroll
        for (int G = 0; G < 3; G++) {
            #pragma unroll
            for (int n = 0; n < 2; n++) {
                unsigned short tmp[8];
                #pragma unroll
                for (int j = 0; j < 8; j++)
                    tmp[j] = f2bf(W_hh[(size_t)(G * HID + u0 + n * 16 + ln) * HID
                                       + k0 + q * 8 + j]);
                whh[ci][G][n] = *(bf16x8*)tmp;
            }
        }
    }

    // ---- biases (per owned output unit), fp32 master h in regs ----
    const int gu = u0 + wn * 16 + ln;
    const float bR  = b_ih[gu]            + b_hh[gu];
    const float bZ  = b_ih[HID + gu]      + b_hh[HID + gu];
    const float bIN = b_ih[2 * HID + gu];
    const float bHN = b_hh[2 * HID + gu];
    float hreg[4] = {0.f, 0.f, 0.f, 0.f};

    const int nxc = (w == 0) ? 3 : 2;  // W_ih K-chunks this wave owns (9 chunks / 4 waves)

    __syncthreads();

    unsigned long long* hbufs[2] = {hb0, hb1};
    unsigned short* htw = htile + w * 384;   // per-wave 16x24 tile (wave-closed)

    for (int t = 0; t < T_STEPS; t++) {
        const unsigned long long* hrd = hbufs[t & 1];
        unsigned long long* hwr = hbufs[(t + 1) & 1];

        f32x4 aR[2][2]  = {{{0,0,0,0},{0,0,0,0}},{{0,0,0,0},{0,0,0,0}}};
        f32x4 aZ[2][2]  = {{{0,0,0,0},{0,0,0,0}},{{0,0,0,0},{0,0,0,0}}};
        f32x4 aIN[2][2] = {{{0,0,0,0},{0,0,0,0}},{{0,0,0,0},{0,0,0,0}}};
        f32x4 aHN[2][2] = {{{0,0,0,0},{0,0,0,0}},{{0,0,0,0},{0,0,0,0}}};

        // ---- x-part (no h dependency — overlaps producer tail) ----
        const unsigned short* xrow = xt + (size_t)t * BATCH * DINP;
        #pragma unroll
        for (int xi = 0; xi < 3; xi++) {
            if (xi < nxc) {
                int kx = (w + xi * 4) * 32;
                bf16x8 a0 = *(const bf16x8*)(xrow + (size_t)(bb +      ln) * DINP + kx + q * 8);
                bf16x8 a1 = *(const bf16x8*)(xrow + (size_t)(bb + 16 + ln) * DINP + kx + q * 8);
                #pragma unroll
                for (int n = 0; n < 2; n++) {
                    const unsigned short* wb = &wih[(size_t)(n * 16 + ln) * WIH_STRIDE + kx + q * 8];
                    bf16x8 br = *(const bf16x8*)(wb);
                    bf16x8 bz = *(const bf16x8*)(wb + 32 * WIH_STRIDE);
                    bf16x8 bn = *(const bf16x8*)(wb + 64 * WIH_STRIDE);
                    aR[0][n]  = __builtin_amdgcn_mfma_f32_16x16x32_bf16(a0, br, aR[0][n],  0, 0, 0);
                    aR[1][n]  = __builtin_amdgcn_mfma_f32_16x16x32_bf16(a1, br, aR[1][n],  0, 0, 0);
                    aZ[0][n]  = __builtin_amdgcn_mfma_f32_16x16x32_bf16(a0, bz, aZ[0][n],  0, 0, 0);
                    aZ[1][n]  = __builtin_amdgcn_mfma_f32_16x16x32_bf16(a1, bz, aZ[1][n],  0, 0, 0);
                    aIN[0][n] = __builtin_amdgcn_mfma_f32_16x16x32_bf16(a0, bn, aIN[0][n], 0, 0, 0);
                    aIN[1][n] = __builtin_amdgcn_mfma_f32_16x16x32_bf16(a1, bn, aIN[1][n], 0, 0, 0);
                }
            }
        }

        // ---- wait for h(t): 128 per-wave slots (32 producer blocks x 4 waves) ----
        if (t > 0 && tid < 128) {
            const unsigned int* slot =
                flags + (((size_t)(t - 1) * BGN + g) << 7) + tid;
            while (__hip_atomic_load(slot, __ATOMIC_RELAXED,
                                     __HIP_MEMORY_SCOPE_AGENT) == 0u)
                __builtin_amdgcn_s_sleep(1);
        }
        __syncthreads();   // [A]

        // ---- h-part: preload ALL fragments via 16B sc0+sc1 loads (16/thread) ----
        const unsigned short* hrd16 = (const unsigned short*)hrd;
        bf16x8 hfrag[8][2];
        __builtin_amdgcn_sched_barrier(0);
        #pragma unroll
        for (int ci = 0; ci < 8; ci++) {
            int k0 = (w + ci * 4) * 32;
            #pragma unroll
            for (int s = 0; s < 2; s++) {
                hfrag[ci][s] = load_h16(
                    hrd16 + (size_t)(bb + s * 16 + ln) * HID + k0 + q * 8);
            }
        }
        asm volatile("s_waitcnt vmcnt(0)" ::: "memory");
        __builtin_amdgcn_sched_barrier(0);   // rule #18: pin MFMAs after the wait

        // ---- h MFMAs: B operands straight from registers ----
        #pragma unroll
        for (int ci = 0; ci < 8; ci++) {
            #pragma unroll
            for (int n = 0; n < 2; n++) {
                aR[0][n]  = __builtin_amdgcn_mfma_f32_16x16x32_bf16(hfrag[ci][0], whh[ci][0][n], aR[0][n],  0, 0, 0);
                aR[1][n]  = __builtin_amdgcn_mfma_f32_16x16x32_bf16(hfrag[ci][1], whh[ci][0][n], aR[1][n],  0, 0, 0);
                aZ[0][n]  = __builtin_amdgcn_mfma_f32_16x16x32_bf16(hfrag[ci][0], whh[ci][1][n], aZ[0][n],  0, 0, 0);
                aZ[1][n]  = __builtin_amdgcn_mfma_f32_16x16x32_bf16(hfrag[ci][1], whh[ci][1][n], aZ[1][n],  0, 0, 0);
                aHN[0][n] = __builtin_amdgcn_mfma_f32_16x16x32_bf16(hfrag[ci][0], whh[ci][2][n], aHN[0][n], 0, 0, 0);
                aHN[1][n] = __builtin_amdgcn_mfma_f32_16x16x32_bf16(hfrag[ci][1], whh[ci][2][n], aHN[1][n], 0, 0, 0);
            }
        }

        // ---- cross-wave K-reduction: write partials for quadrants we don't own ----
        #pragma unroll
        for (int vv = 0; vv < 4; vv++) {
            if (vv != w) {
                const int ss = vv >> 1, nn = vv & 1;
                int j = w - (w > vv ? 1 : 0);
                int base = (vv * 3 + j) * 4;
                #pragma unroll
                for (int r = 0; r < 4; r++) {
                    int ro = (q * 4 + r) * 17 + ln;
                    buf[(base + 0) * 272 + ro] = aR[ss][nn][r];
                    buf[(base + 1) * 272 + ro] = aZ[ss][nn][r];
                    buf[(base + 2) * 272 + ro] = aIN[ss][nn][r];
                    buf[(base + 3) * 272 + ro] = aHN[ss][nn][r];
                }
            }
        }
        __syncthreads();   // [C]

        f32x4 myR  = (w == 0) ? aR[0][0]  : (w == 1) ? aR[0][1]  : (w == 2) ? aR[1][0]  : aR[1][1];
        f32x4 myZ  = (w == 0) ? aZ[0][0]  : (w == 1) ? aZ[0][1]  : (w == 2) ? aZ[1][0]  : aZ[1][1];
        f32x4 myIN = (w == 0) ? aIN[0][0] : (w == 1) ? aIN[0][1] : (w == 2) ? aIN[1][0] : aIN[1][1];
        f32x4 myHN = (w == 0) ? aHN[0][0] : (w == 1) ? aHN[0][1] : (w == 2) ? aHN[1][0] : aHN[1][1];

        float R[4], Z[4], IN[4], HN[4];
        #pragma unroll
        for (int r = 0; r < 4; r++) { R[r] = myR[r]; Z[r] = myZ[r]; IN[r] = myIN[r]; HN[r] = myHN[r]; }
        #pragma unroll
        for (int j = 0; j < 3; j++) {
            int base = (w * 3 + j) * 4;
            #pragma unroll
            for (int r = 0; r < 4; r++) {
                int ro = (q * 4 + r) * 17 + ln;
                R[r]  += buf[(base + 0) * 272 + ro];
                Z[r]  += buf[(base + 1) * 272 + ro];
                IN[r] += buf[(base + 2) * 272 + ro];
                HN[r] += buf[(base + 3) * 272 + ro];
            }
        }

        // ---- gates + state update; h(t+1) bf16 into PER-WAVE htile (wave-closed:
        //      only this wave writes/reads its 16x24 slice; DS is in-order per wave) ----
        #pragma unroll
        for (int r = 0; r < 4; r++) {
            float pr = R[r] + bR;
            float pz = Z[r] + bZ;
            float rg = 1.f / (1.f + expf(-pr));
            float zg = 1.f / (1.f + expf(-pz));
            float ng = tanhf(IN[r] + bIN + rg * (HN[r] + bHN));
            float hn = (1.f - zg) * ng + zg * hreg[r];
            hreg[r] = hn;
            htw[(q * 4 + r) * 24 + ln] = f2bf(hn);
            if (t == T_STEPS - 1)
                hF[(size_t)(bb + ws * 16 + q * 4 + r) * HID + gu] = hn;
        }

        // ---- packed coherent h store (within own quadrant: wave-closed transpose) ----
        {
            int j   = tid & 63;
            int row = j >> 2;            // batch within quadrant 0..15
            int uq  = (j & 3) * 4;       // unit quad 0,4,8,12
            unsigned long long pk = *(const unsigned long long*)(&htw[row * 24 + uq]);
            __hip_atomic_store(hwr + (((size_t)(bb + ws * 16 + row) * HID
                                       + u0 + wn * 16 + uq) >> 2), pk,
                               __ATOMIC_RELAXED, __HIP_MEMORY_SCOPE_AGENT);
        }

        // ---- per-wave release: drain own stores, then set own flag slot ----
        asm volatile("s_waitcnt vmcnt(0)" ::: "memory");
        if ((tid & 63) == 0)
            __hip_atomic_store(flags + (((size_t)t * BGN + g) << 7) + (ut << 2) + w, 1u,
                               __ATOMIC_RELAXED, __HIP_MEMORY_SCOPE_AGENT);
    }
}

// out[b][o] = h[b] . W_out[o] + b_out[o]
__global__ void out_proj(const float* __restrict__ h, const float* __restrict__ Wout,
                         const float* __restrict__ bout, float* __restrict__ out) {
    int b = blockIdx.x;    // 256
    int o = threadIdx.x;   // 128
    const float* hr = h + (size_t)b * HID;
    const float* wr = Wout + (size_t)o * HID;
    float s0 = 0.f, s1 = 0.f, s2 = 0.f, s3 = 0.f;
    for (int u = 0; u < HID; u += 4) {
        s0 += hr[u + 0] * wr[u + 0];
        s1 += hr[u + 1] * wr[u + 1];
        s2 += hr[u + 2] * wr[u + 2];
        s3 += hr[u + 3] * wr[u + 3];
    }
    out[b * OUTD + o] = (s0 + s1) + (s2 + s3) + bout[o];
}

extern "C" void kernel_launch(void* const* d_in, const int* in_sizes, int n_in,
                              void* d_out, int out_size, void* d_ws, size_t ws_size,
                              hipStream_t stream) {
    const float* x     = (const float*)d_in[0];
    const float* mask  = (const float*)d_in[1];
    const float* ti    = (const float*)d_in[2];
    const float* W_ih  = (const float*)d_in[3];
    const float* W_hh  = (const float*)d_in[4];
    const float* b_ih  = (const float*)d_in[5];
    const float* b_hh  = (const float*)d_in[6];
    const float* W_out = (const float*)d_in[7];
    const float* b_out = (const float*)d_in[8];
    float* out = (float*)d_out;

    char* ws = (char*)d_ws;
    unsigned int* flags     = (unsigned int*)ws;                        // 2 MB (512*8*128*4)
    unsigned long long* hb0 = (unsigned long long*)(ws + 2097152);      // 512 KB
    unsigned long long* hb1 = (unsigned long long*)(ws + 2621440);      // 512 KB
    float* hF               = (float*)(ws + 3145728);                   // 1 MB
    unsigned short* xtb     = (unsigned short*)(ws + 4194304);          // 75.5 MB

    // zero flags + h(0) (contiguous)
    (void)hipMemsetAsync(ws, 0, 2621440, stream);

    build_xt<<<4096, 256, 0, stream>>>(x, mask, ti, xtb);

    (void)hipFuncSetAttribute((const void*)gru_persist,
                              hipFuncAttributeMaxDynamicSharedMemorySize, LDS_BYTES);

    gru_persist<<<256, 256, LDS_BYTES, stream>>>(xtb, W_ih, W_hh, b_ih, b_hh,
                                                 hb0, hb1, hF, flags);

    out_proj<<<256, 128, 0, stream>>>(hF, W_out, b_out, out);
}